// Round 6
// baseline (217.507 us; speedup 1.0000x reference)
//
#include <hip/hip_runtime.h>
#include <math.h>
#include <stdint.h>

#define HW   128
#define CIN  64
#define OC   64
#define TW   16          // pixel tile width
#define TH   4           // pixel tile height (one wave per row)
#define HLW  18          // halo width
#define HLH  6           // halo height
#define HLN  (HLW*HLH)   // 108 halo positions
#define SXR  109         // sx row stride (floats)
#define K2   9
#define KTOT (CIN*K2)    // 576
#define SOPR 81          // sop row stride (floats)

typedef __bf16  bf16x8 __attribute__((ext_vector_type(8)));
typedef float   f32x4  __attribute__((ext_vector_type(4)));
typedef uint32_t u32x4 __attribute__((ext_vector_type(4)));

__device__ __forceinline__ ushort f32_to_bf16_rne(float f) {
    union { float f; uint32_t u; } x; x.f = f;
    return (ushort)((x.u + 0x7FFF + ((x.u >> 16) & 1)) >> 16);
}

#define PKBF16(dst, lo, hi) \
    asm("v_cvt_pk_bf16_f32 %0, %1, %2" : "=v"(dst) : "v"(lo), "v"(hi))

// ---- prep: WT[o][kt*64 + c] = bf16(weight[c][o][kt]) ----
__global__ void prep_weight(const float* __restrict__ w, ushort* __restrict__ wt) {
    int n = blockIdx.x * 256 + threadIdx.x;        // 0 .. 36863
    int o = n / KTOT;
    int r = n - o * KTOT;
    int kt = r >> 6;
    int c  = r & 63;
    wt[n] = f32_to_bf16_rne(w[(c * OC + o) * K2 + kt]);
}

__global__ __launch_bounds__(256, 2)
void dyf_main(const float* __restrict__ x,
              const float* __restrict__ bias,
              const float* __restrict__ op_w,
              const float* __restrict__ op_b,
              const ushort* __restrict__ wt,
              float* __restrict__ out)
{
    __shared__ float sx[CIN * SXR];     // 27904 B
    __shared__ float sT[HLN];           //   432 B
    __shared__ float sop[64 * SOPR];    // 20736 B (op' f32, diagonal folded)
                                        // total 49072 B -> 2 blocks/CU

    const int tid  = threadIdx.x;
    const int lane = tid & 63;
    const int wv   = tid >> 6;
    const int b    = blockIdx.z;
    const int h0   = blockIdx.y * TH;
    const int w0   = blockIdx.x * TW;

    // ---- Phase 1: stage x tile + halo (zero-padded, f32) ----
    {
        const float* __restrict__ xb = x + (size_t)b * CIN * HW * HW;
        #pragma unroll
        for (int it = 0; it < 27; ++it) {          // 27*256 = 6912 = CIN*HLN
            int i  = tid + it * 256;
            int c  = i / HLN;
            int r  = i - c * HLN;
            int hy = r / HLW;
            int hx = r - hy * HLW;
            int gy = h0 - 1 + hy;
            int gx = w0 - 1 + hx;
            float v = 0.f;
            if ((unsigned)gy < HW && (unsigned)gx < HW)
                v = xb[c * HW * HW + gy * HW + gx];
            sx[c * SXR + r] = v;
        }
    }
    __syncthreads();

    // ---- Phase 2: T = per-position channel square-sum ----
    if (tid < HLN) {
        float s = 0.f;
        #pragma unroll 16
        for (int c = 0; c < CIN; ++c) { float v = sx[c * SXR + tid]; s += v * v; }
        sT[tid] = s;
    }
    __syncthreads();

    // ---- Phase 3: dynamic operator op'[j][kt] = tanh(.) + (j==kt), f32 ----
    {
        const int px = tid >> 2;                   // 0..63
        const int q  = tid & 3;
        const int py = px >> 4, pxx = px & 15;
        float nrm[9];
        #pragma unroll
        for (int j = 0; j < 9; ++j)
            nrm[j] = sqrtf(sT[(py + j / 3) * HLW + pxx + (j % 3)]);
        const int nkt = (q == 0) ? 3 : 2;
        for (int t = 0; t < 3; ++t) {
            if (t >= nkt) break;
            const int kt = (q == 0) ? ((t == 2) ? 8 : t) : (q * 2 + t);
            #pragma unroll
            for (int j = 0; j < 9; ++j) {
                const int m = j * 9 + kt;
                float a = op_b[m];
                #pragma unroll
                for (int jj = 0; jj < 9; ++jj) a += nrm[jj] * op_w[m * 9 + jj];
                float v = tanhf(a);
                if (j == kt) v += 1.0f;            // fold "+xu" into diagonal
                sop[px * SOPR + m] = v;
            }
        }
    }
    __syncthreads();

    // ---- Phase 4: Z in registers (B-fragment layout) ----
    // Wave wv owns pixel row py=wv; lane: pxx=lane&15 (pixel col), g=lane>>4.
    // Thread holds z[px][k] for k = s*32 + g*8 + i  (kt = s>>1, c = (s&1)*32 + g*8 + i).
    const int pxx = lane & 15;
    const int g   = lane >> 4;
    const int py  = wv;

    float opf[81];
    {
        const float* srcp = &sop[(wv * 16 + pxx) * SOPR];
        #pragma unroll
        for (int m = 0; m < 81; ++m) opf[m] = srcp[m];
    }

    u32x4 zw[18];
    #pragma unroll
    for (int chalf = 0; chalf < 2; ++chalf) {
        #pragma unroll
        for (int t = 0; t < 4; ++t) {
            const int c0 = chalf * 32 + g * 8 + 2 * t;   // channels c0, c0+1
            float xu0[9], xu1[9];
            #pragma unroll
            for (int j = 0; j < 9; ++j) {
                const int pos = (py + j / 3) * HLW + pxx + (j % 3);
                xu0[j] = sx[c0 * SXR + pos];
                xu1[j] = sx[(c0 + 1) * SXR + pos];
            }
            #pragma unroll
            for (int kt = 0; kt < 9; ++kt) {
                float y0 = 0.f, y1 = 0.f;
                #pragma unroll
                for (int j = 0; j < 9; ++j) {
                    y0 += xu0[j] * opf[j * 9 + kt];
                    y1 += xu1[j] * opf[j * 9 + kt];
                }
                uint32_t pk;
                PKBF16(pk, y0, y1);                // lo = c0 (even), hi = c0+1
                zw[2 * kt + chalf][t] = pk;
            }
        }
    }

    __builtin_amdgcn_sched_barrier(0);   // keep A-loads out of the Z region

    // ---- Phase 5: MFMA, A streamed from global (L2-hot wt) ----
    {
        f32x4 acc[4];
        #pragma unroll
        for (int mr = 0; mr < 4; ++mr) acc[mr] = f32x4{0.f, 0.f, 0.f, 0.f};

        #pragma unroll
        for (int s = 0; s < 18; ++s) {
            const bf16x8 bfr = __builtin_bit_cast(bf16x8, zw[s]);
            #pragma unroll
            for (int mr = 0; mr < 4; ++mr) {
                const bf16x8 af = *reinterpret_cast<const bf16x8*>(
                    wt + (mr * 16 + pxx) * KTOT + s * 32 + g * 8);
                acc[mr] = __builtin_amdgcn_mfma_f32_16x16x32_bf16(af, bfr, acc[mr], 0, 0, 0);
            }
        }
        // D: o = mr*16 + g*4 + ii ; col n = px = pxx ; pixel row = wv
        #pragma unroll
        for (int mr = 0; mr < 4; ++mr) {
            #pragma unroll
            for (int ii = 0; ii < 4; ++ii) {
                const int o = mr * 16 + g * 4 + ii;
                out[(((size_t)b * OC + o) * HW + (h0 + wv)) * HW + w0 + pxx]
                    = acc[mr][ii] + bias[o];
            }
        }
    }
}

extern "C" void kernel_launch(void* const* d_in, const int* in_sizes, int n_in,
                              void* d_out, int out_size, void* d_ws, size_t ws_size,
                              hipStream_t stream) {
    const float* x      = (const float*)d_in[0];
    const float* weight = (const float*)d_in[1];
    const float* bias   = (const float*)d_in[2];
    const float* op_w   = (const float*)d_in[3];
    const float* op_b   = (const float*)d_in[4];
    float*  out = (float*)d_out;
    ushort* wt  = (ushort*)d_ws;                   // 73728 B

    prep_weight<<<dim3((OC * KTOT) / 256), dim3(256), 0, stream>>>(weight, wt);

    dim3 grid(HW / TW, HW / TH, 8);                // (8, 32, 8) = 2048 blocks
    dyf_main<<<grid, dim3(256), 0, stream>>>(x, bias, op_w, op_b, wt, out);
}